// Round 10
// baseline (24.592 us; speedup 1.0000x reference)
//
#include <hip/hip_runtime.h>

#define NJ   24
#define BLK  256
#define W    4                  // rows (batch elements) per thread
#define JREC 5                  // float4 slots per joint record (4 data + 1 pad)
#define QMF4 (NJ * JREC)        // float4 index of (Qm) ; +1 = pm
#define NCPY (NJ * JREC + 2)    // float4s in the LDS constant table
#define INV4PI 0.07957747154594767f
#define FOURPI 12.566370614359172f

// SE(3) element as unit quaternion + translation.
struct DQ { float w, x, y, z, t0, t1, t2; };

// Per-joint constants held in registers (13 floats).
struct JC { float W0,W1,W2,h, v0,v1,v2, c10,c11,c12, c20,c21,c22; };

// Compose C = A * B  (rotation: A.q (x) B.q ; translation: A.t + rot(A.q, B.t))
__device__ __forceinline__ DQ dq_comp(const DQ A, const DQ B) {
    const float u10 = A.y*B.t2 - A.z*B.t1;
    const float u11 = A.z*B.t0 - A.x*B.t2;
    const float u12 = A.x*B.t1 - A.y*B.t0;
    const float u20 = A.y*u12 - A.z*u11;
    const float u21 = A.z*u10 - A.x*u12;
    const float u22 = A.x*u11 - A.y*u10;
    const float tw  = 2.0f * A.w;
    DQ C;
    C.t0 = fmaf(tw, u10, fmaf(2.0f, u20, A.t0 + B.t0));
    C.t1 = fmaf(tw, u11, fmaf(2.0f, u21, A.t1 + B.t1));
    C.t2 = fmaf(tw, u12, fmaf(2.0f, u22, A.t2 + B.t2));
    C.w = A.w*B.w - A.x*B.x - A.y*B.y - A.z*B.z;
    C.x = A.w*B.x + A.x*B.w + A.y*B.z - A.z*B.y;
    C.y = A.w*B.y - A.x*B.z + A.y*B.w + A.z*B.x;
    C.z = A.w*B.z + A.x*B.y - A.y*B.x + A.z*B.w;
    return C;
}

// Build exp(a * xi_j) from register constants.  phi = 4*pi*hrev.
__device__ __forceinline__ DQ dq_exp(const JC J, const float a) {
    const float hrev = a * J.h;                   // phi/(4*pi): half-angle revs
    const float sh   = __builtin_amdgcn_sinf(hrev);
    const float ch   = __builtin_amdgcn_cosf(hrev);
    const float s    = 2.0f * sh * ch;            // sin(phi)
    const float cB   = 2.0f * sh * sh;            // 1 - cos(phi)
    const float g    = fmaf(FOURPI, hrev, -s);    // phi - sin(phi)
    DQ e;
    e.w  = ch;
    e.x  = sh * J.W0;
    e.y  = sh * J.W1;
    e.z  = sh * J.W2;
    e.t0 = fmaf(a, J.v0, fmaf(cB, J.c10, g * J.c20));
    e.t1 = fmaf(a, J.v1, fmaf(cB, J.c11, g * J.c21));
    e.t2 = fmaf(a, J.v2, fmaf(cB, J.c12, g * J.c22));
    return e;
}

// ---------------------------------------------------------------------------
// Fused kernel, W rows per thread. Block prep: threads 0..23 build joint
// records in LDS, thread 24 builds exp(M). Each lane q of a row-quad loads
// its 6 joint records ONCE into registers, then grid-strides over W rows:
// build+compose 6 exponentials, 2 __shfl_xor combine rounds, fold exp(M),
// Q->R, store one 16B row per lane (coalesced). x for the next row is
// prefetched before computing the current row.
// ---------------------------------------------------------------------------
__global__ __launch_bounds__(BLK, 4)
void poe_main(const float* __restrict__ x,
              const float* __restrict__ eta,
              const float* __restrict__ M,
              float* __restrict__ out,
              int nBatch)
{
    __shared__ float4 sC[NCPY];
    float* sF = (float*)sC;

    const int t = threadIdx.x;
    if (t < NJ) {
        const float w0 = eta[t*6+0], w1 = eta[t*6+1], w2 = eta[t*6+2];
        const float v0 = eta[t*6+3], v1 = eta[t*6+4], v2 = eta[t*6+5];
        const float k  = w0*w0 + w1*w1 + w2*w2;
        const bool  sm = (k < 1e-12f);
        const float invsqk = sm ? 0.0f : rsqrtf(k);
        const float sqk    = k * invsqk;
        const float invk   = invsqk * invsqk;
        const float invk15 = invk * invsqk;
        const float c10 = w1*v2 - w2*v1;
        const float c11 = w2*v0 - w0*v2;
        const float c12 = w0*v1 - w1*v0;
        const float c20 = w1*c12 - w2*c11;
        const float c21 = w2*c10 - w0*c12;
        const float c22 = w0*c11 - w1*c10;
        float* r = sF + t * JREC * 4;
        r[0]  = w0*invsqk;  r[1]  = w1*invsqk;  r[2]  = w2*invsqk;  r[3]  = sqk;
        r[4]  = v0;         r[5]  = v1;         r[6]  = v2;         r[7]  = sqk * INV4PI;
        r[8]  = c10*invk;   r[9]  = c11*invk;   r[10] = c12*invk;   r[11] = 0.0f;
        r[12] = c20*invk15; r[13] = c21*invk15; r[14] = c22*invk15; r[15] = 0.0f;
    } else if (t == NJ) {
        const float w0 = M[0], w1 = M[1], w2 = M[2];
        const float v0 = M[3], v1 = M[4], v2 = M[5];
        const float t2 = w0*w0 + w1*w1 + w2*w2;
        const bool  sm = (t2 < 1e-12f);
        const float t2s  = sm ? 1.0f : t2;
        const float invt = rsqrtf(t2s);
        const float th   = t2s * invt;
        float s, c;
        __sincosf(th, &s, &c);
        const float invt2 = invt * invt;
        const float B = sm ? 0.5f        : (1.0f - c) * invt2;
        const float C = sm ? (1.0f/6.0f) : (th - s) * invt2 * invt;
        float sh, chh;
        __sincosf(0.5f * th, &sh, &chh);
        const float axs = sm ? 0.5f : sh * invt;   // sin(th/2)/th (limit 1/2)
        float* r = sF + QMF4 * 4;
        r[0] = sm ? 1.0f : chh;
        r[1] = axs * w0;
        r[2] = axs * w1;
        r[3] = axs * w2;
        const float c10 = w1*v2 - w2*v1, c11 = w2*v0 - w0*v2, c12 = w0*v1 - w1*v0;
        const float c20 = w1*c12 - w2*c11, c21 = w2*c10 - w0*c12, c22 = w0*c11 - w1*c10;
        r[4] = v0 + B*c10 + C*c20;
        r[5] = v1 + B*c11 + C*c21;
        r[6] = v2 + B*c12 + C*c22;
        r[7] = 0.0f;
    }

    const int gid    = blockIdx.x * BLK + t;
    const int tq     = gid >> 2;               // row-quad index
    const int q      = gid & 3;
    const int stride = (gridDim.x * BLK) >> 2; // row step between i-iterations

    __syncthreads();

    // ---- load this lane's 6 joint records ONCE into registers ----
    JC jc[6];
    const int cbase = q * 6 * JREC;
    #pragma unroll
    for (int j = 0; j < 6; ++j) {
        const float4 A4 = sC[cbase + j*JREC + 0];
        const float4 B4 = sC[cbase + j*JREC + 1];
        const float4 C4 = sC[cbase + j*JREC + 2];
        const float4 D4 = sC[cbase + j*JREC + 3];
        jc[j].W0 = A4.x; jc[j].W1 = A4.y; jc[j].W2 = A4.z; jc[j].h = B4.w;
        jc[j].v0 = B4.x; jc[j].v1 = B4.y; jc[j].v2 = B4.z;
        jc[j].c10 = C4.x; jc[j].c11 = C4.y; jc[j].c12 = C4.z;
        jc[j].c20 = D4.x; jc[j].c21 = D4.y; jc[j].c22 = D4.z;
    }

    // exp(M) as registers (broadcast read, uniform across block)
    const float4 Qm = sC[QMF4];
    const float4 Pm = sC[QMF4 + 1];
    DQ Em;
    Em.w = Qm.x; Em.x = Qm.y; Em.y = Qm.z; Em.z = Qm.w;
    Em.t0 = Pm.x; Em.t1 = Pm.y; Em.t2 = Pm.z;

    // ---- prefetch row 0 ----
    int row = tq;
    float2 xa = make_float2(0.f,0.f), xb = xa, xc = xa;
    if (row < nBatch) {
        const float2* xp = (const float2*)(x + (size_t)row * NJ + q * 6);
        xa = xp[0]; xb = xp[1]; xc = xp[2];
    }

    #pragma unroll
    for (int i = 0; i < W; ++i) {
        // prefetch next row's angles (overlaps with compute below)
        const int nrow = row + stride;
        float2 nxa = make_float2(0.f,0.f), nxb = nxa, nxc = nxa;
        if (i < W-1 && nrow < nBatch) {
            const float2* xp = (const float2*)(x + (size_t)nrow * NJ + q * 6);
            nxa = xp[0]; nxb = xp[1]; nxc = xp[2];
        }

        // ---- sequential compose of this lane's 6 joints ----
        DQ T = dq_exp(jc[0], xa.x);
        T = dq_comp(T, dq_exp(jc[1], xa.y));
        T = dq_comp(T, dq_exp(jc[2], xb.x));
        T = dq_comp(T, dq_exp(jc[3], xb.y));
        T = dq_comp(T, dq_exp(jc[4], xc.x));
        T = dq_comp(T, dq_exp(jc[5], xc.y));

        // ---- combine within the quad: rounds xor-1, xor-2 ----
#define COMBINE(BIT) do {                                                     \
        DQ O;                                                                 \
        O.w  = __shfl_xor(T.w,  BIT);  O.x  = __shfl_xor(T.x,  BIT);          \
        O.y  = __shfl_xor(T.y,  BIT);  O.z  = __shfl_xor(T.z,  BIT);          \
        O.t0 = __shfl_xor(T.t0, BIT);  O.t1 = __shfl_xor(T.t1, BIT);          \
        O.t2 = __shfl_xor(T.t2, BIT);                                         \
        const bool up = (q & (BIT)) != 0;   /* self is the SECOND factor */   \
        DQ A, B;                                                              \
        A.w  = up ? O.w  : T.w;   B.w  = up ? T.w  : O.w;                     \
        A.x  = up ? O.x  : T.x;   B.x  = up ? T.x  : O.x;                     \
        A.y  = up ? O.y  : T.y;   B.y  = up ? T.y  : O.y;                     \
        A.z  = up ? O.z  : T.z;   B.z  = up ? T.z  : O.z;                     \
        A.t0 = up ? O.t0 : T.t0;  B.t0 = up ? T.t0 : O.t0;                    \
        A.t1 = up ? O.t1 : T.t1;  B.t1 = up ? T.t1 : O.t1;                    \
        A.t2 = up ? O.t2 : T.t2;  B.t2 = up ? T.t2 : O.t2;                    \
        T = dq_comp(A, B);                                                    \
} while (0)

        COMBINE(1);
        COMBINE(2);
#undef COMBINE

        // ---- fold exp(M) ----
        T = dq_comp(T, Em);

        // ---- Q -> R, pick my row, store (coalesced 16B/lane) ----
        if (row < nBatch) {
            const float xx = T.x*T.x, yy = T.y*T.y, zz = T.z*T.z;
            const float xy = T.x*T.y, xz = T.x*T.z, yz = T.y*T.z;
            const float wx = T.w*T.x, wy = T.w*T.y, wz = T.w*T.z;
            const float R00 = 1.0f - 2.0f*(yy + zz);
            const float R01 = 2.0f*(xy - wz);
            const float R02 = 2.0f*(xz + wy);
            const float R10 = 2.0f*(xy + wz);
            const float R11 = 1.0f - 2.0f*(xx + zz);
            const float R12 = 2.0f*(yz - wx);
            const float R20 = 2.0f*(xz - wy);
            const float R21 = 2.0f*(yz + wx);
            const float R22 = 1.0f - 2.0f*(xx + yy);

            float4 mine;
            if      (q == 0) mine = make_float4(R00, R01, R02, T.t0);
            else if (q == 1) mine = make_float4(R10, R11, R12, T.t1);
            else if (q == 2) mine = make_float4(R20, R21, R22, T.t2);
            else             mine = make_float4(0.0f, 0.0f, 0.0f, 1.0f);

            ((float4*)out)[(size_t)row * 4 + q] = mine;
        }

        row = nrow;
        xa = nxa; xb = nxb; xc = nxc;
    }
}

extern "C" void kernel_launch(void* const* d_in, const int* in_sizes, int n_in,
                              void* d_out, int out_size, void* d_ws, size_t ws_size,
                              hipStream_t stream)
{
    const float* x   = (const float*)d_in[0];
    const float* eta = (const float*)d_in[1];
    const float* M   = (const float*)d_in[2];
    float* out = (float*)d_out;

    const int nBatch   = in_sizes[0] / NJ;
    const int nQuads   = (nBatch + W - 1) / W;      // row-quads (threads/4)
    const int nThreads = nQuads * 4;
    const int grid     = (nThreads + BLK - 1) / BLK;

    poe_main<<<grid, BLK, 0, stream>>>(x, eta, M, out, nBatch);
}

// Round 11
// 20.359 us; speedup vs baseline: 1.2080x; 1.2080x over previous
//
#include <hip/hip_runtime.h>

#define NJ   24
#define BLK  256
#define JREC 5                  // float4 slots per joint record (4 data + 1 pad)
#define QMF4 (NJ * JREC)        // float4 index of (Qm) ; +1 = pm
#define NCPY (NJ * JREC + 2)    // float4s in the LDS constant table
#define INV4PI 0.07957747154594767f

// ---------------------------------------------------------------------------
// Single fused kernel (R8 structure, occupancy-forced).
// Block prep: threads 0..23 build joint records in LDS, thread 24 builds
// exp(M) as (quat, trans). Then 4 lanes per batch row: lane q owns joints
// 6q..6q+5 as a sequential quaternion chain, 2 __shfl_xor combine rounds,
// fold exp(M), Q->R, store one 16B row per lane (fully coalesced).
// __launch_bounds__(256, 8): cap VGPR at 64 -> 8 waves/SIMD (100% occupancy).
// ---------------------------------------------------------------------------
__global__ __launch_bounds__(BLK, 8)
void poe_main(const float* __restrict__ x,
              const float* __restrict__ eta,
              const float* __restrict__ M,
              float* __restrict__ out,
              int nBatch)
{
    __shared__ float4 sC[NCPY];
    float* sF = (float*)sC;

    const int t = threadIdx.x;
    if (t < NJ) {
        const float w0 = eta[t*6+0], w1 = eta[t*6+1], w2 = eta[t*6+2];
        const float v0 = eta[t*6+3], v1 = eta[t*6+4], v2 = eta[t*6+5];
        const float k  = w0*w0 + w1*w1 + w2*w2;
        const bool  sm = (k < 1e-12f);
        const float invsqk = sm ? 0.0f : rsqrtf(k);
        const float sqk    = k * invsqk;
        const float invk   = invsqk * invsqk;
        const float invk15 = invk * invsqk;
        const float c10 = w1*v2 - w2*v1;
        const float c11 = w2*v0 - w0*v2;
        const float c12 = w0*v1 - w1*v0;
        const float c20 = w1*c12 - w2*c11;
        const float c21 = w2*c10 - w0*c12;
        const float c22 = w0*c11 - w1*c10;
        float* r = sF + t * JREC * 4;
        r[0]  = w0*invsqk;  r[1]  = w1*invsqk;  r[2]  = w2*invsqk;  r[3]  = sqk;
        r[4]  = v0;         r[5]  = v1;         r[6]  = v2;         r[7]  = sqk * INV4PI;
        r[8]  = c10*invk;   r[9]  = c11*invk;   r[10] = c12*invk;   r[11] = 0.0f;
        r[12] = c20*invk15; r[13] = c21*invk15; r[14] = c22*invk15; r[15] = 0.0f;
    } else if (t == NJ) {
        const float w0 = M[0], w1 = M[1], w2 = M[2];
        const float v0 = M[3], v1 = M[4], v2 = M[5];
        const float t2 = w0*w0 + w1*w1 + w2*w2;
        const bool  sm = (t2 < 1e-12f);
        const float t2s  = sm ? 1.0f : t2;
        const float invt = rsqrtf(t2s);
        const float th   = t2s * invt;
        float s, c;
        __sincosf(th, &s, &c);
        const float invt2 = invt * invt;
        const float B = sm ? 0.5f        : (1.0f - c) * invt2;
        const float C = sm ? (1.0f/6.0f) : (th - s) * invt2 * invt;
        float sh, chh;
        __sincosf(0.5f * th, &sh, &chh);
        const float axs = sm ? 0.5f : sh * invt;   // sin(th/2)/th (limit 1/2)
        float* r = sF + QMF4 * 4;
        r[0] = sm ? 1.0f : chh;
        r[1] = axs * w0;
        r[2] = axs * w1;
        r[3] = axs * w2;
        const float c10 = w1*v2 - w2*v1, c11 = w2*v0 - w0*v2, c12 = w0*v1 - w1*v0;
        const float c20 = w1*c12 - w2*c11, c21 = w2*c10 - w0*c12, c22 = w0*c11 - w1*c10;
        r[4] = v0 + B*c10 + C*c20;
        r[5] = v1 + B*c11 + C*c21;
        r[6] = v2 + B*c12 + C*c22;
        r[7] = 0.0f;
    }

    // ---- own 6 joint angles (independent of LDS prep; issue before sync) ----
    const int gid = blockIdx.x * BLK + t;
    const int row = gid >> 2;
    const int q   = gid & 3;
    const bool active = row < nBatch;

    float2 xa = make_float2(0.f,0.f), xb = xa, xc = xa;
    if (active) {
        const float2* xp = (const float2*)(x + (size_t)row * NJ + q * 6);
        xa = xp[0]; xb = xp[1]; xc = xp[2];
    }

    __syncthreads();

    float Qw=1.f, Qx=0.f, Qy=0.f, Qz=0.f;
    float p0=0.f, p1=0.f, p2=0.f;

    const int cbase = q * 6 * JREC;   // float4 index of this lane's first record

#define JSTEP(JJ, A_) do {                                                    \
    const float4 A4 = sC[cbase + (JJ)*JREC + 0];                              \
    const float4 B4 = sC[cbase + (JJ)*JREC + 1];                              \
    const float4 C4 = sC[cbase + (JJ)*JREC + 2];                              \
    const float4 D4 = sC[cbase + (JJ)*JREC + 3];                              \
    const float a    = (A_);                                                  \
    const float hrev = a * B4.w;                                              \
    const float sh   = __builtin_amdgcn_sinf(hrev);                           \
    const float ch   = __builtin_amdgcn_cosf(hrev);                           \
    const float s    = 2.0f * sh * ch;          /* sin(phi)   */              \
    const float cB   = 2.0f * sh * sh;          /* 1-cos(phi) */              \
    const float phi  = a * A4.w;                                              \
    const float g    = phi - s;                                               \
    const float qj0 = fmaf(a, B4.x, fmaf(cB, C4.x, g * D4.x));                \
    const float qj1 = fmaf(a, B4.y, fmaf(cB, C4.y, g * D4.y));                \
    const float qj2 = fmaf(a, B4.z, fmaf(cB, C4.z, g * D4.z));                \
    const float u10 = Qy*qj2 - Qz*qj1;                                        \
    const float u11 = Qz*qj0 - Qx*qj2;                                        \
    const float u12 = Qx*qj1 - Qy*qj0;                                        \
    const float u20 = Qy*u12 - Qz*u11;                                        \
    const float u21 = Qz*u10 - Qx*u12;                                        \
    const float u22 = Qx*u11 - Qy*u10;                                        \
    const float tw  = 2.0f * Qw;                                              \
    p0 = fmaf(tw, u10, fmaf(2.0f, u20, p0 + qj0));                            \
    p1 = fmaf(tw, u11, fmaf(2.0f, u21, p1 + qj1));                            \
    p2 = fmaf(tw, u12, fmaf(2.0f, u22, p2 + qj2));                            \
    const float ex = sh * A4.x, ey = sh * A4.y, ez = sh * A4.z;               \
    const float nQw = Qw*ch - Qx*ex - Qy*ey - Qz*ez;                          \
    const float nQx = Qw*ex + Qx*ch + Qy*ez - Qz*ey;                          \
    const float nQy = Qw*ey - Qx*ez + Qy*ch + Qz*ex;                          \
    const float nQz = Qw*ez + Qx*ey - Qy*ex + Qz*ch;                          \
    Qw=nQw; Qx=nQx; Qy=nQy; Qz=nQz;                                           \
} while (0)

    JSTEP(0, xa.x); JSTEP(1, xa.y); JSTEP(2, xb.x);
    JSTEP(3, xb.y); JSTEP(4, xc.x); JSTEP(5, xc.y);
#undef JSTEP

    // ---- combine within the quad: rounds xor-1, xor-2 ----
#define COMBINE(BIT) do {                                                     \
    const float oQw = __shfl_xor(Qw, BIT), oQx = __shfl_xor(Qx, BIT);         \
    const float oQy = __shfl_xor(Qy, BIT), oQz = __shfl_xor(Qz, BIT);         \
    const float op0 = __shfl_xor(p0, BIT), op1 = __shfl_xor(p1, BIT);         \
    const float op2 = __shfl_xor(p2, BIT);                                    \
    const bool up = (q & (BIT)) != 0;   /* self is the SECOND factor */       \
    const float Aw = up ? oQw : Qw, Ax = up ? oQx : Qx;                       \
    const float Ay = up ? oQy : Qy, Az = up ? oQz : Qz;                       \
    const float Ap0 = up ? op0 : p0, Ap1 = up ? op1 : p1, Ap2 = up ? op2 : p2;\
    const float Bw = up ? Qw : oQw, Bx = up ? Qx : oQx;                       \
    const float By = up ? Qy : oQy, Bz = up ? Qz : oQz;                       \
    const float Bp0 = up ? p0 : op0, Bp1 = up ? p1 : op1, Bp2 = up ? p2 : op2;\
    const float u10 = Ay*Bp2 - Az*Bp1;                                        \
    const float u11 = Az*Bp0 - Ax*Bp2;                                        \
    const float u12 = Ax*Bp1 - Ay*Bp0;                                        \
    const float u20 = Ay*u12 - Az*u11;                                        \
    const float u21 = Az*u10 - Ax*u12;                                        \
    const float u22 = Ax*u11 - Ay*u10;                                        \
    const float tw  = 2.0f * Aw;                                              \
    p0 = fmaf(tw, u10, fmaf(2.0f, u20, Ap0 + Bp0));                           \
    p1 = fmaf(tw, u11, fmaf(2.0f, u21, Ap1 + Bp1));                           \
    p2 = fmaf(tw, u12, fmaf(2.0f, u22, Ap2 + Bp2));                           \
    Qw = Aw*Bw - Ax*Bx - Ay*By - Az*Bz;                                       \
    Qx = Aw*Bx + Ax*Bw + Ay*Bz - Az*By;                                       \
    Qy = Aw*By - Ax*Bz + Ay*Bw + Az*Bx;                                       \
    Qz = Aw*Bz + Ax*By - Ay*Bx + Az*Bw;                                       \
} while (0)

    COMBINE(1);
    COMBINE(2);
#undef COMBINE

    // ---- fold exp(M): T = T * Em  (Em = (Qm, pm), re-read from LDS) ----
    {
        const float4 Qm = sC[QMF4];
        const float4 Pm = sC[QMF4 + 1];
        const float u10 = Qy*Pm.z - Qz*Pm.y;
        const float u11 = Qz*Pm.x - Qx*Pm.z;
        const float u12 = Qx*Pm.y - Qy*Pm.x;
        const float u20 = Qy*u12 - Qz*u11;
        const float u21 = Qz*u10 - Qx*u12;
        const float u22 = Qx*u11 - Qy*u10;
        const float tw  = 2.0f * Qw;
        p0 = fmaf(tw, u10, fmaf(2.0f, u20, p0 + Pm.x));
        p1 = fmaf(tw, u11, fmaf(2.0f, u21, p1 + Pm.y));
        p2 = fmaf(tw, u12, fmaf(2.0f, u22, p2 + Pm.z));
        const float nQw = Qw*Qm.x - Qx*Qm.y - Qy*Qm.z - Qz*Qm.w;
        const float nQx = Qw*Qm.y + Qx*Qm.x + Qy*Qm.w - Qz*Qm.z;
        const float nQy = Qw*Qm.z - Qx*Qm.w + Qy*Qm.x + Qz*Qm.y;
        const float nQz = Qw*Qm.w + Qx*Qm.z - Qy*Qm.y + Qz*Qm.x;
        Qw=nQw; Qx=nQx; Qy=nQy; Qz=nQz;
    }

    // ---- Q -> R, pick my row, store (coalesced 16B/lane) ----
    if (active) {
        const float xx = Qx*Qx, yy = Qy*Qy, zz = Qz*Qz;
        const float xy = Qx*Qy, xz = Qx*Qz, yz = Qy*Qz;
        const float wx = Qw*Qx, wy = Qw*Qy, wz = Qw*Qz;
        const float R00 = 1.0f - 2.0f*(yy + zz);
        const float R01 = 2.0f*(xy - wz);
        const float R02 = 2.0f*(xz + wy);
        const float R10 = 2.0f*(xy + wz);
        const float R11 = 1.0f - 2.0f*(xx + zz);
        const float R12 = 2.0f*(yz - wx);
        const float R20 = 2.0f*(xz - wy);
        const float R21 = 2.0f*(yz + wx);
        const float R22 = 1.0f - 2.0f*(xx + yy);

        float4 mine;
        if      (q == 0) mine = make_float4(R00, R01, R02, p0);
        else if (q == 1) mine = make_float4(R10, R11, R12, p1);
        else if (q == 2) mine = make_float4(R20, R21, R22, p2);
        else             mine = make_float4(0.0f, 0.0f, 0.0f, 1.0f);

        ((float4*)out)[(size_t)row * 4 + q] = mine;
    }
}

extern "C" void kernel_launch(void* const* d_in, const int* in_sizes, int n_in,
                              void* d_out, int out_size, void* d_ws, size_t ws_size,
                              hipStream_t stream)
{
    const float* x   = (const float*)d_in[0];
    const float* eta = (const float*)d_in[1];
    const float* M   = (const float*)d_in[2];
    float* out = (float*)d_out;

    const int nBatch   = in_sizes[0] / NJ;
    const int nThreads = nBatch * 4;
    const int grid     = (nThreads + BLK - 1) / BLK;

    poe_main<<<grid, BLK, 0, stream>>>(x, eta, M, out, nBatch);
}